// Round 1
// baseline (459.559 us; speedup 1.0000x reference)
//
#include <hip/hip_runtime.h>
#include <hip/hip_bf16.h>
#include <cstdint>

#define B_ 4
#define T_ 2048
#define D_ 512
#define H_ 8
#define DH_ 64

typedef __bf16 bf16x8 __attribute__((ext_vector_type(8)));
typedef __bf16 bf16x4 __attribute__((ext_vector_type(4)));
typedef float f32x4 __attribute__((ext_vector_type(4)));

// ---------------- cast fp32 -> bf16 (vectorized) ----------------
__global__ void cast_kernel(const float* __restrict__ in, __bf16* __restrict__ out, int n4) {
    int stride = gridDim.x * blockDim.x;
    for (int i = blockIdx.x * blockDim.x + threadIdx.x; i < n4; i += stride) {
        float4 v = reinterpret_cast<const float4*>(in)[i];
        bf16x4 o = { (__bf16)v.x, (__bf16)v.y, (__bf16)v.z, (__bf16)v.w };
        reinterpret_cast<bf16x4*>(out)[i] = o;
    }
}

// ---------------- transpose W (R x C fp32) -> WT (C x R bf16) ----------------
__global__ void transpose_w_kernel(const float* __restrict__ in, __bf16* __restrict__ out,
                                   int R, int C) {
    __shared__ float tile[32][33];
    int tx = threadIdx.x & 31, ty = threadIdx.x >> 5;   // 32 x 8
    int r0 = blockIdx.y * 32, c0 = blockIdx.x * 32;
#pragma unroll
    for (int i = 0; i < 4; i++)
        tile[ty + i * 8][tx] = in[(size_t)(r0 + ty + i * 8) * C + c0 + tx];
    __syncthreads();
#pragma unroll
    for (int i = 0; i < 4; i++)
        out[(size_t)(c0 + ty + i * 8) * R + r0 + tx] = (__bf16)tile[tx][ty + i * 8];
}

// ---------------- transpose V: tmp fp32 [B][T][H*64] -> vt bf16 [B*H][64][T] ----------------
__global__ void transpose_v_kernel(const float* __restrict__ in, __bf16* __restrict__ out) {
    __shared__ float tile[32][33];
    int z = blockIdx.z; int b = z / H_, h = z % H_;
    const float* src = in + (size_t)b * T_ * D_ + h * 64;
    __bf16* dst = out + (size_t)z * 64 * T_;
    int t0 = blockIdx.x * 32, d0 = blockIdx.y * 32;
    int tx = threadIdx.x & 31, ty = threadIdx.x >> 5;
#pragma unroll
    for (int i = 0; i < 4; i++)
        tile[ty + i * 8][tx] = src[(size_t)(t0 + ty + i * 8) * D_ + d0 + tx];
    __syncthreads();
#pragma unroll
    for (int i = 0; i < 4; i++)
        dst[(size_t)(d0 + ty + i * 8) * T_ + t0 + tx] = (__bf16)tile[tx][ty + i * 8];
}

// ---------------- GEMM: out(MxN fp32) = X(MxK bf16) @ WT(NxK bf16)^T + bias ----------------
// One wave computes a 16x64 output tile. A/B fragments use the SAME k-mapping
// (lane-hi*8+j), so the MFMA contraction is correct for any HW k-order.
__global__ void gemm_kernel(const __bf16* __restrict__ X, const __bf16* __restrict__ WT,
                            const float* __restrict__ bias, float* __restrict__ out,
                            int M, int N, int K) {
    int lane = threadIdx.x & 63, widx = threadIdx.x >> 6;
    int lo = lane & 15, hi = lane >> 4;
    int wglob = blockIdx.x * 4 + widx;
    int ntn = N >> 6;
    int m0 = (wglob / ntn) << 4;
    int n0 = (wglob % ntn) << 6;
    f32x4 acc[4] = {};
    const __bf16* xrow = X + (size_t)(m0 + lo) * K + hi * 8;
    for (int kc = 0; kc < K; kc += 32) {
        bf16x8 a = *reinterpret_cast<const bf16x8*>(xrow + kc);
#pragma unroll
        for (int n = 0; n < 4; n++) {
            bf16x8 b = *reinterpret_cast<const bf16x8*>(WT + (size_t)(n0 + n * 16 + lo) * K + kc + hi * 8);
            acc[n] = __builtin_amdgcn_mfma_f32_16x16x32_bf16(a, b, acc[n], 0, 0, 0);
        }
    }
#pragma unroll
    for (int n = 0; n < 4; n++)
#pragma unroll
        for (int r = 0; r < 4; r++) {
            int mm = m0 + hi * 4 + r, nn = n0 + n * 16 + lo;
            out[(size_t)mm * N + nn] = acc[n][r] + bias[nn];
        }
}

// ---------------- fused RMSNorm + RoPE epilogue ----------------
// proj fp32 [B*T][512] viewed as [B][T][H][64] -> heads bf16 [B*H][T][64]
__global__ void rmsrope_kernel(const float* __restrict__ proj, const float* __restrict__ scale,
                               const int* __restrict__ pos, __bf16* __restrict__ outh) {
    int lane = threadIdx.x & 63;
    int gw = blockIdx.x * 4 + (threadIdx.x >> 6);  // (b*T+t)*H + h
    int h = gw % H_; int bt = gw / H_;
    int b = bt / T_, t = bt % T_;
    float x = proj[(size_t)bt * D_ + h * 64 + lane];
    float ss = x * x;
#pragma unroll
    for (int off = 1; off < 64; off <<= 1) ss += __shfl_xor(ss, off);
    float r = rsqrtf(ss * (1.0f / 64.0f) + 1e-6f);
    float y = x * r * (1.0f + scale[lane]);
    int p = pos[bt];
    int d2 = lane & 31;
    float ts = powf(10000.0f, (float)d2 * (1.0f / 32.0f));
    float ang = (float)p / ts;
    float sv, cv;
    sincosf(ang, &sv, &cv);
    float partner = __shfl_xor(y, 32);
    float outv = (lane < 32) ? (y * cv - partner * sv) : (y * cv + partner * sv);
    outh[((size_t)(b * H_ + h) * T_ + t) * 64 + lane] = (__bf16)outv;
}

// ---------------- causal flash attention ----------------
// qh, kh: bf16 [B*H][T][64]; vt: bf16 [B*H][64][T]; attn out: bf16 [B*T][512]
// Block = 4 waves; wave w owns 16 q-rows (qb = blockIdx.x*64 + w*16).
__global__ void attn_kernel(const __bf16* __restrict__ qh, const __bf16* __restrict__ kh,
                            const __bf16* __restrict__ vt, __bf16* __restrict__ attn) {
    __shared__ __bf16 plds[4][16][32];
    int lane = threadIdx.x & 63, widx = threadIdx.x >> 6;
    int lo = lane & 15, hi = lane >> 4;
    int bh = blockIdx.y;
    int qb = blockIdx.x * 64 + widx * 16;
    const __bf16* Q = qh + (size_t)bh * T_ * 64;
    const __bf16* K = kh + (size_t)bh * T_ * 64;
    const __bf16* V = vt + (size_t)bh * 64 * T_;

    bf16x8 qa[2];
#pragma unroll
    for (int c = 0; c < 2; c++)
        qa[c] = *reinterpret_cast<const bf16x8*>(Q + (size_t)(qb + lo) * 64 + c * 32 + hi * 8);

    f32x4 o[4] = {};
    float m[4], l[4];
#pragma unroll
    for (int r = 0; r < 4; r++) { m[r] = -1e30f; l[r] = 0.0f; }

    int kvend = qb + 16;
    for (int kvb = 0; kvb < kvend; kvb += 32) {
        f32x4 s0 = {}, s1 = {};
#pragma unroll
        for (int c = 0; c < 2; c++) {
            bf16x8 k0 = *reinterpret_cast<const bf16x8*>(K + (size_t)(kvb + lo) * 64 + c * 32 + hi * 8);
            bf16x8 k1 = *reinterpret_cast<const bf16x8*>(K + (size_t)(kvb + 16 + lo) * 64 + c * 32 + hi * 8);
            s0 = __builtin_amdgcn_mfma_f32_16x16x32_bf16(qa[c], k0, s0, 0, 0, 0);
            s1 = __builtin_amdgcn_mfma_f32_16x16x32_bf16(qa[c], k1, s1, 0, 0, 0);
        }
        const float sc = 0.125f;  // 1/sqrt(64)
        bool needmask = (kvb + 31 > qb);
        float p0[4], p1[4], pm[4];
#pragma unroll
        for (int r = 0; r < 4; r++) {
            float a0 = s0[r] * sc, a1 = s1[r] * sc;
            if (needmask) {
                int q = qb + hi * 4 + r;
                if (kvb + lo > q) a0 = -1e30f;
                if (kvb + 16 + lo > q) a1 = -1e30f;
            }
            p0[r] = a0; p1[r] = a1;
            pm[r] = fmaxf(a0, a1);
        }
#pragma unroll
        for (int r = 0; r < 4; r++) {
#pragma unroll
            for (int off = 1; off < 16; off <<= 1) pm[r] = fmaxf(pm[r], __shfl_xor(pm[r], off));
        }
        float alpha[4];
#pragma unroll
        for (int r = 0; r < 4; r++) {
            float mn = fmaxf(m[r], pm[r]);
            alpha[r] = __expf(m[r] - mn);
            m[r] = mn;
            p0[r] = __expf(p0[r] - mn);
            p1[r] = __expf(p1[r] - mn);
            float ps = p0[r] + p1[r];
#pragma unroll
            for (int off = 1; off < 16; off <<= 1) ps += __shfl_xor(ps, off);
            l[r] = l[r] * alpha[r] + ps;
        }
#pragma unroll
        for (int n = 0; n < 4; n++)
#pragma unroll
            for (int r = 0; r < 4; r++) o[n][r] *= alpha[r];

        // P (16x32) -> per-wave LDS -> A-fragment (same k-mapping as B loads)
#pragma unroll
        for (int r = 0; r < 4; r++) {
            plds[widx][hi * 4 + r][lo] = (__bf16)p0[r];
            plds[widx][hi * 4 + r][16 + lo] = (__bf16)p1[r];
        }
        bf16x8 pa = *reinterpret_cast<const bf16x8*>(&plds[widx][lo][hi * 8]);
#pragma unroll
        for (int n = 0; n < 4; n++) {
            bf16x8 vb = *reinterpret_cast<const bf16x8*>(V + (size_t)(n * 16 + lo) * T_ + kvb + hi * 8);
            o[n] = __builtin_amdgcn_mfma_f32_16x16x32_bf16(pa, vb, o[n], 0, 0, 0);
        }
    }

    int b = bh / H_, h = bh % H_;
#pragma unroll
    for (int r = 0; r < 4; r++) {
        float inv = 1.0f / l[r];
        int q = qb + hi * 4 + r;
#pragma unroll
        for (int n = 0; n < 4; n++)
            attn[((size_t)b * T_ + q) * D_ + h * 64 + n * 16 + lo] = (__bf16)(o[n][r] * inv);
    }
}

extern "C" void kernel_launch(void* const* d_in, const int* in_sizes, int n_in,
                              void* d_out, int out_size, void* d_ws, size_t ws_size,
                              hipStream_t stream) {
    const float* q  = (const float*)d_in[0];
    const float* kv = (const float*)d_in[1];
    // d_in[2] = mask (bool tril) — causal, handled analytically
    const int* qpos = (const int*)d_in[3];
    const int* kpos = (const int*)d_in[4];
    const float* wq = (const float*)d_in[5];
    const float* bq = (const float*)d_in[6];
    const float* wk = (const float*)d_in[7];
    const float* bk = (const float*)d_in[8];
    const float* wv = (const float*)d_in[9];
    const float* bv = (const float*)d_in[10];
    const float* scale_q = (const float*)d_in[11];
    const float* scale_k = (const float*)d_in[12];
    const float* wo = (const float*)d_in[13];
    const float* bo = (const float*)d_in[14];
    float* out = (float*)d_out;

    char* ws = (char*)d_ws;
    size_t off = 0;
    auto alloc = [&](size_t bytes) {
        void* p = ws + off;
        off += (bytes + 255) & ~(size_t)255;
        return p;
    };
    const size_t MD = (size_t)B_ * T_ * D_;  // 4,194,304
    __bf16* qb16  = (__bf16*)alloc(MD * 2);
    __bf16* kvb16 = (__bf16*)alloc(MD * 2);
    __bf16* wqT = (__bf16*)alloc((size_t)D_ * D_ * 2);
    __bf16* wkT = (__bf16*)alloc((size_t)D_ * D_ * 2);
    __bf16* wvT = (__bf16*)alloc((size_t)D_ * D_ * 2);
    __bf16* woT = (__bf16*)alloc((size_t)D_ * D_ * 2);
    float*  tmp = (float*)alloc(MD * 4);
    __bf16* qh  = (__bf16*)alloc(MD * 2);
    __bf16* kh  = (__bf16*)alloc(MD * 2);
    __bf16* vt  = (__bf16*)alloc(MD * 2);
    __bf16* attn = qb16;  // reuse: qb16 dead after the Q GEMM

    // input casts
    cast_kernel<<<2048, 256, 0, stream>>>(q, qb16, (int)(MD / 4));
    cast_kernel<<<2048, 256, 0, stream>>>(kv, kvb16, (int)(MD / 4));
    // weight transposes (fp32 -> bf16, [K][N] -> [N][K])
    dim3 twg(16, 16, 1);
    transpose_w_kernel<<<twg, 256, 0, stream>>>(wq, wqT, D_, D_);
    transpose_w_kernel<<<twg, 256, 0, stream>>>(wk, wkT, D_, D_);
    transpose_w_kernel<<<twg, 256, 0, stream>>>(wv, wvT, D_, D_);
    transpose_w_kernel<<<twg, 256, 0, stream>>>(wo, woT, D_, D_);

    const int M = B_ * T_;
    const int gemm_blocks = (M / 16) * (D_ / 64) / 4;  // 1024

    // Q path
    gemm_kernel<<<gemm_blocks, 256, 0, stream>>>(qb16, wqT, bq, tmp, M, D_, D_);
    rmsrope_kernel<<<(B_ * T_ * H_) / 4, 256, 0, stream>>>(tmp, scale_q, qpos, qh);
    // K path
    gemm_kernel<<<gemm_blocks, 256, 0, stream>>>(kvb16, wkT, bk, tmp, M, D_, D_);
    rmsrope_kernel<<<(B_ * T_ * H_) / 4, 256, 0, stream>>>(tmp, scale_k, kpos, kh);
    // V path
    gemm_kernel<<<gemm_blocks, 256, 0, stream>>>(kvb16, wvT, bv, tmp, M, D_, D_);
    transpose_v_kernel<<<dim3(T_ / 32, 2, B_ * H_), 256, 0, stream>>>(tmp, vt);
    // attention
    attn_kernel<<<dim3(T_ / 64, B_ * H_), 256, 0, stream>>>(qh, kh, vt, attn);
    // output projection
    gemm_kernel<<<gemm_blocks, 256, 0, stream>>>(attn, woT, bo, out, M, D_, D_);
}

// Round 2
// 277.290 us; speedup vs baseline: 1.6573x; 1.6573x over previous
//
#include <hip/hip_runtime.h>
#include <hip/hip_bf16.h>
#include <cstdint>

#define B_ 4
#define T_ 2048
#define D_ 512
#define H_ 8

typedef __bf16 bf16x8 __attribute__((ext_vector_type(8)));
typedef __bf16 bf16x4 __attribute__((ext_vector_type(4)));
typedef float f32x4 __attribute__((ext_vector_type(4)));

__device__ inline void gload_lds16(const void* g, void* l) {
    __builtin_amdgcn_global_load_lds(
        (const __attribute__((address_space(1))) void*)g,
        (__attribute__((address_space(3))) void*)l, 16, 0, 0);
}

// ---------------- cast fp32 -> bf16 (vectorized) ----------------
__global__ void cast_kernel(const float* __restrict__ in, __bf16* __restrict__ out, int n4) {
    int stride = gridDim.x * blockDim.x;
    for (int i = blockIdx.x * blockDim.x + threadIdx.x; i < n4; i += stride) {
        float4 v = reinterpret_cast<const float4*>(in)[i];
        bf16x4 o = { (__bf16)v.x, (__bf16)v.y, (__bf16)v.z, (__bf16)v.w };
        reinterpret_cast<bf16x4*>(out)[i] = o;
    }
}

// ---------------- transpose W (R x C fp32) -> WT (C x R bf16) ----------------
__global__ void transpose_w_kernel(const float* __restrict__ in, __bf16* __restrict__ out,
                                   int R, int C) {
    __shared__ float tile[32][33];
    int tx = threadIdx.x & 31, ty = threadIdx.x >> 5;   // 32 x 8
    int r0 = blockIdx.y * 32, c0 = blockIdx.x * 32;
#pragma unroll
    for (int i = 0; i < 4; i++)
        tile[ty + i * 8][tx] = in[(size_t)(r0 + ty + i * 8) * C + c0 + tx];
    __syncthreads();
#pragma unroll
    for (int i = 0; i < 4; i++)
        out[(size_t)(c0 + ty + i * 8) * R + r0 + tx] = (__bf16)tile[tx][ty + i * 8];
}

// ---------------- transpose V: tmp fp32 [B][T][H*64] -> vt bf16 [B*H][64][T] ----------------
__global__ void transpose_v_kernel(const float* __restrict__ in, __bf16* __restrict__ out) {
    __shared__ float tile[32][33];
    int z = blockIdx.z; int b = z / H_, h = z % H_;
    const float* src = in + (size_t)b * T_ * D_ + h * 64;
    __bf16* dst = out + (size_t)z * 64 * T_;
    int t0 = blockIdx.x * 32, d0 = blockIdx.y * 32;
    int tx = threadIdx.x & 31, ty = threadIdx.x >> 5;
#pragma unroll
    for (int i = 0; i < 4; i++)
        tile[ty + i * 8][tx] = src[(size_t)(t0 + ty + i * 8) * D_ + d0 + tx];
    __syncthreads();
#pragma unroll
    for (int i = 0; i < 4; i++)
        dst[(size_t)(d0 + ty + i * 8) * T_ + t0 + tx] = (__bf16)tile[tx][ty + i * 8];
}

// ---------------- GEMM: out(MxN fp32) = X(MxK bf16) @ WT(NxK bf16)^T + bias ----------------
__global__ void gemm_kernel(const __bf16* __restrict__ X, const __bf16* __restrict__ WT,
                            const float* __restrict__ bias, float* __restrict__ out,
                            int M, int N, int K) {
    int lane = threadIdx.x & 63, widx = threadIdx.x >> 6;
    int lo = lane & 15, hi = lane >> 4;
    int wglob = blockIdx.x * 4 + widx;
    int ntn = N >> 6;
    int m0 = (wglob / ntn) << 4;
    int n0 = (wglob % ntn) << 6;
    f32x4 acc[4] = {};
    const __bf16* xrow = X + (size_t)(m0 + lo) * K + hi * 8;
    for (int kc = 0; kc < K; kc += 32) {
        bf16x8 a = *reinterpret_cast<const bf16x8*>(xrow + kc);
#pragma unroll
        for (int n = 0; n < 4; n++) {
            bf16x8 b = *reinterpret_cast<const bf16x8*>(WT + (size_t)(n0 + n * 16 + lo) * K + kc + hi * 8);
            acc[n] = __builtin_amdgcn_mfma_f32_16x16x32_bf16(a, b, acc[n], 0, 0, 0);
        }
    }
#pragma unroll
    for (int n = 0; n < 4; n++)
#pragma unroll
        for (int r = 0; r < 4; r++) {
            int mm = m0 + hi * 4 + r, nn = n0 + n * 16 + lo;
            out[(size_t)mm * N + nn] = acc[n][r] + bias[nn];
        }
}

// ---------------- fused RMSNorm + RoPE epilogue ----------------
__global__ void rmsrope_kernel(const float* __restrict__ proj, const float* __restrict__ scale,
                               const int* __restrict__ pos, __bf16* __restrict__ outh) {
    int lane = threadIdx.x & 63;
    int gw = blockIdx.x * 4 + (threadIdx.x >> 6);  // (b*T+t)*H + h
    int h = gw % H_; int bt = gw / H_;
    int b = bt / T_, t = bt % T_;
    float x = proj[(size_t)bt * D_ + h * 64 + lane];
    float ss = x * x;
#pragma unroll
    for (int off = 1; off < 64; off <<= 1) ss += __shfl_xor(ss, off);
    float r = rsqrtf(ss * (1.0f / 64.0f) + 1e-6f);
    float y = x * r * (1.0f + scale[lane]);
    int p = pos[bt];
    int d2 = lane & 31;
    // 1/timescale = 2^(-d2 * log2(10000)/32)
    float inv_ts = exp2f((float)d2 * (-13.28771237954945f / 32.0f));
    float ang = (float)p * inv_ts;
    float sv, cv;
    __sincosf(ang, &sv, &cv);
    float partner = __shfl_xor(y, 32);
    float outv = (lane < 32) ? (y * cv - partner * sv) : (y * cv + partner * sv);
    outh[((size_t)(b * H_ + h) * T_ + t) * 64 + lane] = (__bf16)outv;
}

// ---------------- causal flash attention (pipelined, LDS-staged KV) ----------------
// qh, kh: bf16 [B*H][T][64]; vt: bf16 [B*H][64][T]; attn out: bf16 [B*T][512]
// Block = 4 waves; each wave owns 16 q-rows of a 64-row strip. Each block
// processes strips (x, 31-x) -> uniform 33 KV-tiles/block (causal balance).
// K/V staged per 64-row KV tile in LDS (16B-chunk XOR swizzle, G21:
// inverse-swizzled global source + linear global_load_lds dest + swizzled read),
// double-buffered with prefetch-before-compute (T3 minimum recipe).
__global__ __launch_bounds__(256, 2) void attn_kernel(const __bf16* __restrict__ qh,
                                                      const __bf16* __restrict__ kh,
                                                      const __bf16* __restrict__ vt,
                                                      __bf16* __restrict__ attn) {
    __shared__ __bf16 kbuf[2][64 * 64];
    __shared__ __bf16 vbuf[2][64 * 64];
    __shared__ __bf16 plds[4][16][68];   // stride 68 elems: conflict-free writes

    const int lane = threadIdx.x & 63, widx = threadIdx.x >> 6;
    const int lo = lane & 15, hi = lane >> 4;
    const int bh = blockIdx.y;
    const __bf16* Qg = qh + (size_t)bh * T_ * 64;
    const __bf16* Kg = kh + (size_t)bh * T_ * 64;
    const __bf16* Vg = vt + (size_t)bh * 64 * T_;
    const int b = bh >> 3, h = bh & 7;

    // staging decomposition: one global_load_lds covers 8 rows x 128B.
    // lane -> row r0+srow, 16B slot sslot; slot sslot must hold logical chunk
    // schunk = sslot ^ (r&7)  (r&7 == srow since r0 % 8 == 0).
    const int srow = lane >> 3;
    const int sslot = lane & 7;
    const int schunk = sslot ^ srow;

    for (int strip = 0; strip < 2; ++strip) {
        const int sid = strip ? (31 - blockIdx.x) : blockIdx.x;
        const int qb = sid * 64 + widx * 16;
        const int ntiles = sid + 1;

        bf16x8 qa[2];
#pragma unroll
        for (int c = 0; c < 2; c++)
            qa[c] = *reinterpret_cast<const bf16x8*>(Qg + (size_t)(qb + lo) * 64 + c * 32 + hi * 8);

        f32x4 o[4] = {};
        float m[4], l[4];
#pragma unroll
        for (int r = 0; r < 4; r++) { m[r] = -1e30f; l[r] = 0.0f; }

        auto stage = [&](int tile, int bufi) {
            const int kvb0 = tile * 64;
#pragma unroll
            for (int i = 0; i < 2; i++) {
                int r = widx * 16 + i * 8 + srow;
                gload_lds16(Kg + (size_t)(kvb0 + r) * 64 + schunk * 8,
                            &kbuf[bufi][(widx * 16 + i * 8) * 64]);
            }
#pragma unroll
            for (int i = 0; i < 2; i++) {
                int r = widx * 16 + i * 8 + srow;
                gload_lds16(Vg + (size_t)r * T_ + kvb0 + schunk * 8,
                            &vbuf[bufi][(widx * 16 + i * 8) * 64]);
            }
        };

        stage(0, 0);
        __syncthreads();   // emits vmcnt(0) drain + barrier
        int cur = 0;

        for (int j = 0; j < ntiles; ++j) {
            if (j + 1 < ntiles) stage(j + 1, cur ^ 1);  // prefetch overlaps compute

            // ---- QK^T: S (16 q x 64 kv) ----
            f32x4 s[4] = {};
#pragma unroll
            for (int c = 0; c < 2; c++) {
#pragma unroll
                for (int f = 0; f < 4; f++) {
                    int R = f * 16 + lo;
                    int C = c * 4 + hi;
                    bf16x8 kb = *reinterpret_cast<const bf16x8*>(
                        &kbuf[cur][R * 64 + ((C ^ (lo & 7)) << 3)]);
                    s[f] = __builtin_amdgcn_mfma_f32_16x16x32_bf16(qa[c], kb, s[f], 0, 0, 0);
                }
            }

            // ---- masked scale + online softmax ----
            const float sc = 0.125f;
            const bool diag = (j == ntiles - 1);
            float p[4][4], pm[4];
#pragma unroll
            for (int r = 0; r < 4; r++) pm[r] = -1e30f;
#pragma unroll
            for (int f = 0; f < 4; f++)
#pragma unroll
                for (int r = 0; r < 4; r++) {
                    float a = s[f][r] * sc;
                    if (diag && (f * 16 + lo > widx * 16 + hi * 4 + r)) a = -1e30f;
                    p[f][r] = a;
                    pm[r] = fmaxf(pm[r], a);
                }
#pragma unroll
            for (int r = 0; r < 4; r++) {
#pragma unroll
                for (int off = 1; off < 16; off <<= 1) pm[r] = fmaxf(pm[r], __shfl_xor(pm[r], off));
            }
            float alpha[4];
#pragma unroll
            for (int r = 0; r < 4; r++) {
                float mn = fmaxf(m[r], pm[r]);
                alpha[r] = __expf(m[r] - mn);
                m[r] = mn;
                float ps = 0.0f;
#pragma unroll
                for (int f = 0; f < 4; f++) { p[f][r] = __expf(p[f][r] - mn); ps += p[f][r]; }
#pragma unroll
                for (int off = 1; off < 16; off <<= 1) ps += __shfl_xor(ps, off);
                l[r] = l[r] * alpha[r] + ps;
            }
#pragma unroll
            for (int n = 0; n < 4; n++)
#pragma unroll
                for (int r = 0; r < 4; r++) o[n][r] *= alpha[r];

            // ---- P -> LDS (per-wave) -> A-fragments ----
#pragma unroll
            for (int f = 0; f < 4; f++)
#pragma unroll
                for (int r = 0; r < 4; r++)
                    plds[widx][hi * 4 + r][f * 16 + lo] = (__bf16)p[f][r];
            bf16x8 pa0 = *reinterpret_cast<const bf16x8*>(&plds[widx][lo][hi * 8]);
            bf16x8 pa1 = *reinterpret_cast<const bf16x8*>(&plds[widx][lo][32 + hi * 8]);

            // ---- PV ----
#pragma unroll
            for (int n = 0; n < 4; n++) {
#pragma unroll
                for (int kh2 = 0; kh2 < 2; kh2++) {
                    int R = n * 16 + lo;
                    int C = kh2 * 4 + hi;
                    bf16x8 vb = *reinterpret_cast<const bf16x8*>(
                        &vbuf[cur][R * 64 + ((C ^ (lo & 7)) << 3)]);
                    o[n] = __builtin_amdgcn_mfma_f32_16x16x32_bf16(kh2 ? pa1 : pa0, vb, o[n], 0, 0, 0);
                }
            }

            __syncthreads();   // drains prefetch (vmcnt 0) + closes reads of buf[cur]
            cur ^= 1;
        }

#pragma unroll
        for (int r = 0; r < 4; r++) {
            float inv = 1.0f / l[r];
            int q = qb + hi * 4 + r;
#pragma unroll
            for (int n = 0; n < 4; n++)
                attn[((size_t)b * T_ + q) * D_ + h * 64 + n * 16 + lo] = (__bf16)(o[n][r] * inv);
        }
    }
}

extern "C" void kernel_launch(void* const* d_in, const int* in_sizes, int n_in,
                              void* d_out, int out_size, void* d_ws, size_t ws_size,
                              hipStream_t stream) {
    const float* q  = (const float*)d_in[0];
    const float* kv = (const float*)d_in[1];
    const int* qpos = (const int*)d_in[3];
    const int* kpos = (const int*)d_in[4];
    const float* wq = (const float*)d_in[5];
    const float* bq = (const float*)d_in[6];
    const float* wk = (const float*)d_in[7];
    const float* bk = (const float*)d_in[8];
    const float* wv = (const float*)d_in[9];
    const float* bv = (const float*)d_in[10];
    const float* scale_q = (const float*)d_in[11];
    const float* scale_k = (const float*)d_in[12];
    const float* wo = (const float*)d_in[13];
    const float* bo = (const float*)d_in[14];
    float* out = (float*)d_out;

    char* ws = (char*)d_ws;
    size_t off = 0;
    auto alloc = [&](size_t bytes) {
        void* p = ws + off;
        off += (bytes + 255) & ~(size_t)255;
        return p;
    };
    const size_t MD = (size_t)B_ * T_ * D_;
    __bf16* qb16  = (__bf16*)alloc(MD * 2);
    __bf16* kvb16 = (__bf16*)alloc(MD * 2);
    __bf16* wqT = (__bf16*)alloc((size_t)D_ * D_ * 2);
    __bf16* wkT = (__bf16*)alloc((size_t)D_ * D_ * 2);
    __bf16* wvT = (__bf16*)alloc((size_t)D_ * D_ * 2);
    __bf16* woT = (__bf16*)alloc((size_t)D_ * D_ * 2);
    float*  tmp = (float*)alloc(MD * 4);
    __bf16* qh  = (__bf16*)alloc(MD * 2);
    __bf16* kh  = (__bf16*)alloc(MD * 2);
    __bf16* vt  = (__bf16*)alloc(MD * 2);
    __bf16* attn = qb16;  // reuse: qb16 dead after the Q GEMM

    cast_kernel<<<2048, 256, 0, stream>>>(q, qb16, (int)(MD / 4));
    cast_kernel<<<2048, 256, 0, stream>>>(kv, kvb16, (int)(MD / 4));
    dim3 twg(16, 16, 1);
    transpose_w_kernel<<<twg, 256, 0, stream>>>(wq, wqT, D_, D_);
    transpose_w_kernel<<<twg, 256, 0, stream>>>(wk, wkT, D_, D_);
    transpose_w_kernel<<<twg, 256, 0, stream>>>(wv, wvT, D_, D_);
    transpose_w_kernel<<<twg, 256, 0, stream>>>(wo, woT, D_, D_);

    const int M = B_ * T_;
    const int gemm_blocks = (M / 16) * (D_ / 64) / 4;  // 1024

    gemm_kernel<<<gemm_blocks, 256, 0, stream>>>(qb16, wqT, bq, tmp, M, D_, D_);
    rmsrope_kernel<<<(B_ * T_ * H_) / 4, 256, 0, stream>>>(tmp, scale_q, qpos, qh);
    gemm_kernel<<<gemm_blocks, 256, 0, stream>>>(kvb16, wkT, bk, tmp, M, D_, D_);
    rmsrope_kernel<<<(B_ * T_ * H_) / 4, 256, 0, stream>>>(tmp, scale_k, kpos, kh);
    gemm_kernel<<<gemm_blocks, 256, 0, stream>>>(kvb16, wvT, bv, tmp, M, D_, D_);
    transpose_v_kernel<<<dim3(T_ / 32, 2, B_ * H_), 256, 0, stream>>>(tmp, vt);
    attn_kernel<<<dim3(16, B_ * H_), 256, 0, stream>>>(qh, kh, vt, attn);
    gemm_kernel<<<gemm_blocks, 256, 0, stream>>>(attn, woT, bo, out, M, D_, D_);
}

// Round 3
// 149.895 us; speedup vs baseline: 3.0659x; 1.8499x over previous
//
#include <hip/hip_runtime.h>
#include <hip/hip_bf16.h>
#include <cstdint>

#define B_ 4
#define T_ 2048
#define D_ 512
#define H_ 8

typedef __bf16 bf16x8 __attribute__((ext_vector_type(8)));
typedef __bf16 bf16x4 __attribute__((ext_vector_type(4)));
typedef float f32x4 __attribute__((ext_vector_type(4)));

__device__ inline void gload_lds16(const void* g, void* l) {
    __builtin_amdgcn_global_load_lds(
        (const __attribute__((address_space(1))) void*)g,
        (__attribute__((address_space(3))) void*)l, 16, 0, 0);
}

// ---------------- cast fp32 -> bf16 (vectorized) ----------------
__global__ void cast_kernel(const float* __restrict__ in, __bf16* __restrict__ out, int n4) {
    int stride = gridDim.x * blockDim.x;
    for (int i = blockIdx.x * blockDim.x + threadIdx.x; i < n4; i += stride) {
        float4 v = reinterpret_cast<const float4*>(in)[i];
        bf16x4 o = { (__bf16)v.x, (__bf16)v.y, (__bf16)v.z, (__bf16)v.w };
        reinterpret_cast<bf16x4*>(out)[i] = o;
    }
}

// ---------------- transpose W (R x C fp32) -> WT (C x R bf16) ----------------
__global__ void transpose_w_kernel(const float* __restrict__ in, __bf16* __restrict__ out,
                                   int R, int C) {
    __shared__ float tile[32][33];
    int tx = threadIdx.x & 31, ty = threadIdx.x >> 5;   // 32 x 8
    int r0 = blockIdx.y * 32, c0 = blockIdx.x * 32;
#pragma unroll
    for (int i = 0; i < 4; i++)
        tile[ty + i * 8][tx] = in[(size_t)(r0 + ty + i * 8) * C + c0 + tx];
    __syncthreads();
#pragma unroll
    for (int i = 0; i < 4; i++)
        out[(size_t)(c0 + ty + i * 8) * R + r0 + tx] = (__bf16)tile[tx][ty + i * 8];
}

// ---------------- RoPE cos/sin table: rtab[p][d2] = (cos, sin), p in [0,T), d2 in [0,32) ----------------
__global__ void rope_table_kernel(float2* __restrict__ tab) {
    int i = blockIdx.x * 256 + threadIdx.x;     // 65536 entries
    int p = i >> 5, d2 = i & 31;
    float inv_ts = exp2f((float)d2 * (-13.28771237954945f / 32.0f));
    float ang = (float)p * inv_ts;
    float sv, cv;
    __sincosf(ang, &sv, &cv);
    tab[i] = make_float2(cv, sv);
}

// ---------------- tiled GEMM: 128x128 tile, BK=32, double-buffered LDS ----------------
// out(MxN) = X(MxK bf16) @ WT(NxK bf16)^T + bias, with fused epilogue:
//   MODE 0: fp32 out [M][N]                       (output projection)
//   MODE 1: RMSNorm + RoPE -> bf16 heads [B*H][T][64]   (Q/K paths)
//   MODE 2: bf16 transposed [B*H][64][T]          (V path)
// LDS staging: linear global_load_lds dest, inverse-swizzled global source,
// swizzled ds_read (slot = chunk ^ ((row>>1)&3)) -> conflict-free b128 reads.
template<int MODE>
__global__ __launch_bounds__(256, 2) void gemm_tile_kernel(
    const __bf16* __restrict__ X, const __bf16* __restrict__ WT,
    const float* __restrict__ bias, float* __restrict__ outf,
    __bf16* __restrict__ outh, const float* __restrict__ scale,
    const int* __restrict__ pos, const float2* __restrict__ rtab,
    int M, int N, int K) {
    __shared__ __bf16 Ab[2][128 * 32];
    __shared__ __bf16 Bb[2][128 * 32];

    const int tid = threadIdx.x;
    const int lane = tid & 63, widx = tid >> 6;
    const int lo = lane & 15, hi = lane >> 4;
    const int wm = widx >> 1, wn = widx & 1;

    // bijective XCD swizzle: nwg = 256, 32 blocks/XCD, XCD owns 8 contiguous mtiles
    int bid = blockIdx.x;
    int swz = (bid & 7) * 32 + (bid >> 3);
    const int ntn = N >> 7;
    const int m0 = (swz / ntn) << 7;
    const int n0 = (swz % ntn) << 7;

    // staging: thread -> (row = tid>>2 within 64-row half, slot = tid&3)
    const int srow = tid >> 2;
    const int sslot = tid & 3;

    f32x4 acc[4][4] = {};

    auto stage = [&](int kc, int bufi) {
#pragma unroll
        for (int i = 0; i < 2; i++) {
            int row = i * 64 + srow;
            int cs = sslot ^ ((row >> 1) & 3);
            gload_lds16(X + (size_t)(m0 + row) * K + kc + cs * 8,
                        &Ab[bufi][(i * 64 + widx * 16) * 32]);
        }
#pragma unroll
        for (int i = 0; i < 2; i++) {
            int row = i * 64 + srow;
            int cs = sslot ^ ((row >> 1) & 3);
            gload_lds16(WT + (size_t)(n0 + row) * K + kc + cs * 8,
                        &Bb[bufi][(i * 64 + widx * 16) * 32]);
        }
    };

    const int nks = K >> 5;
    stage(0, 0);
    __syncthreads();
    int cur = 0;

    for (int ks = 0; ks < nks; ks++) {
        if (ks + 1 < nks) stage((ks + 1) << 5, cur ^ 1);

        bf16x8 a[4], bvec[4];
#pragma unroll
        for (int mf = 0; mf < 4; mf++) {
            int R = wm * 64 + mf * 16 + lo;
            a[mf] = *reinterpret_cast<const bf16x8*>(&Ab[cur][R * 32 + ((hi ^ ((R >> 1) & 3)) << 3)]);
        }
#pragma unroll
        for (int nf = 0; nf < 4; nf++) {
            int R = wn * 64 + nf * 16 + lo;
            bvec[nf] = *reinterpret_cast<const bf16x8*>(&Bb[cur][R * 32 + ((hi ^ ((R >> 1) & 3)) << 3)]);
        }
#pragma unroll
        for (int mf = 0; mf < 4; mf++)
#pragma unroll
            for (int nf = 0; nf < 4; nf++)
                acc[mf][nf] = __builtin_amdgcn_mfma_f32_16x16x32_bf16(a[mf], bvec[nf], acc[mf][nf], 0, 0, 0);

        __syncthreads();
        cur ^= 1;
    }

    const int mrow0 = m0 + wm * 64;
    const int ncol0 = n0 + wn * 64;
    float bs[4];
#pragma unroll
    for (int nf = 0; nf < 4; nf++) bs[nf] = bias[ncol0 + nf * 16 + lo];

    if (MODE == 0) {
#pragma unroll
        for (int mf = 0; mf < 4; mf++)
#pragma unroll
            for (int nf = 0; nf < 4; nf++)
#pragma unroll
                for (int r = 0; r < 4; r++) {
                    int row = mrow0 + mf * 16 + hi * 4 + r;
                    outf[(size_t)row * N + ncol0 + nf * 16 + lo] = acc[mf][nf][r] + bs[nf];
                }
    } else if (MODE == 1) {
        float sc4[4];
#pragma unroll
        for (int nf = 0; nf < 4; nf++) sc4[nf] = 1.0f + scale[nf * 16 + lo];
        const int h = ncol0 >> 6;
#pragma unroll
        for (int mf = 0; mf < 4; mf++) {
#pragma unroll
            for (int r = 0; r < 4; r++) {
                int row = mrow0 + mf * 16 + hi * 4 + r;
                float y0 = acc[mf][0][r] + bs[0];
                float y1 = acc[mf][1][r] + bs[1];
                float y2 = acc[mf][2][r] + bs[2];
                float y3 = acc[mf][3][r] + bs[3];
                float ps = y0 * y0 + y1 * y1 + y2 * y2 + y3 * y3;
#pragma unroll
                for (int off = 1; off < 16; off <<= 1) ps += __shfl_xor(ps, off);
                float rmsf = rsqrtf(ps * (1.0f / 64.0f) + 1e-6f);
                int p = pos[row];
                float2 c0 = rtab[p * 32 + lo];
                float2 c1 = rtab[p * 32 + 16 + lo];
                float z0 = y0 * rmsf * sc4[0];
                float z1 = y1 * rmsf * sc4[1];
                float z2 = y2 * rmsf * sc4[2];
                float z3 = y3 * rmsf * sc4[3];
                int b = row >> 11, t = row & (T_ - 1);
                __bf16* dst = outh + ((size_t)(b * H_ + h) * T_ + t) * 64;
                dst[lo]      = (__bf16)(z0 * c0.x - z2 * c0.y);
                dst[16 + lo] = (__bf16)(z1 * c1.x - z3 * c1.y);
                dst[32 + lo] = (__bf16)(z2 * c0.x + z0 * c0.y);
                dst[48 + lo] = (__bf16)(z3 * c1.x + z1 * c1.y);
            }
        }
    } else {  // MODE 2: V transposed
        const int h = ncol0 >> 6;
#pragma unroll
        for (int mf = 0; mf < 4; mf++) {
            int row0 = mrow0 + mf * 16 + hi * 4;
            int b = row0 >> 11, t0 = row0 & (T_ - 1);
#pragma unroll
            for (int nf = 0; nf < 4; nf++) {
                int d = nf * 16 + lo;
                bf16x4 pk = { (__bf16)(acc[mf][nf][0] + bs[nf]), (__bf16)(acc[mf][nf][1] + bs[nf]),
                              (__bf16)(acc[mf][nf][2] + bs[nf]), (__bf16)(acc[mf][nf][3] + bs[nf]) };
                *reinterpret_cast<bf16x4*>(outh + ((size_t)(b * H_ + h) * 64 + d) * T_ + t0) = pk;
            }
        }
    }
}

// ---------------- causal flash attention (pipelined, LDS-staged KV) ----------------
__global__ __launch_bounds__(256, 2) void attn_kernel(const __bf16* __restrict__ qh,
                                                      const __bf16* __restrict__ kh,
                                                      const __bf16* __restrict__ vt,
                                                      __bf16* __restrict__ attn) {
    __shared__ __bf16 kbuf[2][64 * 64];
    __shared__ __bf16 vbuf[2][64 * 64];
    __shared__ __bf16 plds[4][16][68];

    const int lane = threadIdx.x & 63, widx = threadIdx.x >> 6;
    const int lo = lane & 15, hi = lane >> 4;
    const int bh = blockIdx.y;
    const __bf16* Qg = qh + (size_t)bh * T_ * 64;
    const __bf16* Kg = kh + (size_t)bh * T_ * 64;
    const __bf16* Vg = vt + (size_t)bh * 64 * T_;
    const int b = bh >> 3, h = bh & 7;

    const int srow = lane >> 3;
    const int sslot = lane & 7;
    const int schunk = sslot ^ srow;

    for (int strip = 0; strip < 2; ++strip) {
        const int sid = strip ? (31 - blockIdx.x) : blockIdx.x;
        const int qb = sid * 64 + widx * 16;
        const int ntiles = sid + 1;

        bf16x8 qa[2];
#pragma unroll
        for (int c = 0; c < 2; c++)
            qa[c] = *reinterpret_cast<const bf16x8*>(Qg + (size_t)(qb + lo) * 64 + c * 32 + hi * 8);

        f32x4 o[4] = {};
        float m[4], l[4];
#pragma unroll
        for (int r = 0; r < 4; r++) { m[r] = -1e30f; l[r] = 0.0f; }

        auto stage = [&](int tile, int bufi) {
            const int kvb0 = tile * 64;
#pragma unroll
            for (int i = 0; i < 2; i++) {
                int r = widx * 16 + i * 8 + srow;
                gload_lds16(Kg + (size_t)(kvb0 + r) * 64 + schunk * 8,
                            &kbuf[bufi][(widx * 16 + i * 8) * 64]);
            }
#pragma unroll
            for (int i = 0; i < 2; i++) {
                int r = widx * 16 + i * 8 + srow;
                gload_lds16(Vg + (size_t)r * T_ + kvb0 + schunk * 8,
                            &vbuf[bufi][(widx * 16 + i * 8) * 64]);
            }
        };

        stage(0, 0);
        __syncthreads();
        int cur = 0;

        for (int j = 0; j < ntiles; ++j) {
            if (j + 1 < ntiles) stage(j + 1, cur ^ 1);

            f32x4 s[4] = {};
#pragma unroll
            for (int c = 0; c < 2; c++) {
#pragma unroll
                for (int f = 0; f < 4; f++) {
                    int R = f * 16 + lo;
                    int C = c * 4 + hi;
                    bf16x8 kb = *reinterpret_cast<const bf16x8*>(
                        &kbuf[cur][R * 64 + ((C ^ (lo & 7)) << 3)]);
                    s[f] = __builtin_amdgcn_mfma_f32_16x16x32_bf16(qa[c], kb, s[f], 0, 0, 0);
                }
            }

            const float sc = 0.125f;
            const bool diag = (j == ntiles - 1);
            float p[4][4], pm[4];
#pragma unroll
            for (int r = 0; r < 4; r++) pm[r] = -1e30f;
#pragma unroll
            for (int f = 0; f < 4; f++)
#pragma unroll
                for (int r = 0; r < 4; r++) {
                    float a = s[f][r] * sc;
                    if (diag && (f * 16 + lo > widx * 16 + hi * 4 + r)) a = -1e30f;
                    p[f][r] = a;
                    pm[r] = fmaxf(pm[r], a);
                }
#pragma unroll
            for (int r = 0; r < 4; r++) {
#pragma unroll
                for (int off = 1; off < 16; off <<= 1) pm[r] = fmaxf(pm[r], __shfl_xor(pm[r], off));
            }
            float alpha[4];
#pragma unroll
            for (int r = 0; r < 4; r++) {
                float mn = fmaxf(m[r], pm[r]);
                alpha[r] = __expf(m[r] - mn);
                m[r] = mn;
                float ps = 0.0f;
#pragma unroll
                for (int f = 0; f < 4; f++) { p[f][r] = __expf(p[f][r] - mn); ps += p[f][r]; }
#pragma unroll
                for (int off = 1; off < 16; off <<= 1) ps += __shfl_xor(ps, off);
                l[r] = l[r] * alpha[r] + ps;
            }
#pragma unroll
            for (int n = 0; n < 4; n++)
#pragma unroll
                for (int r = 0; r < 4; r++) o[n][r] *= alpha[r];

#pragma unroll
            for (int f = 0; f < 4; f++)
#pragma unroll
                for (int r = 0; r < 4; r++)
                    plds[widx][hi * 4 + r][f * 16 + lo] = (__bf16)p[f][r];
            bf16x8 pa0 = *reinterpret_cast<const bf16x8*>(&plds[widx][lo][hi * 8]);
            bf16x8 pa1 = *reinterpret_cast<const bf16x8*>(&plds[widx][lo][32 + hi * 8]);

#pragma unroll
            for (int n = 0; n < 4; n++) {
#pragma unroll
                for (int kh2 = 0; kh2 < 2; kh2++) {
                    int R = n * 16 + lo;
                    int C = kh2 * 4 + hi;
                    bf16x8 vb = *reinterpret_cast<const bf16x8*>(
                        &vbuf[cur][R * 64 + ((C ^ (lo & 7)) << 3)]);
                    o[n] = __builtin_amdgcn_mfma_f32_16x16x32_bf16(kh2 ? pa1 : pa0, vb, o[n], 0, 0, 0);
                }
            }

            __syncthreads();
            cur ^= 1;
        }

#pragma unroll
        for (int r = 0; r < 4; r++) {
            float inv = 1.0f / l[r];
            int q = qb + hi * 4 + r;
#pragma unroll
            for (int n = 0; n < 4; n++)
                attn[((size_t)b * T_ + q) * D_ + h * 64 + n * 16 + lo] = (__bf16)(o[n][r] * inv);
        }
    }
}

extern "C" void kernel_launch(void* const* d_in, const int* in_sizes, int n_in,
                              void* d_out, int out_size, void* d_ws, size_t ws_size,
                              hipStream_t stream) {
    const float* q  = (const float*)d_in[0];
    const float* kv = (const float*)d_in[1];
    const int* qpos = (const int*)d_in[3];
    const int* kpos = (const int*)d_in[4];
    const float* wq = (const float*)d_in[5];
    const float* bq = (const float*)d_in[6];
    const float* wk = (const float*)d_in[7];
    const float* bk = (const float*)d_in[8];
    const float* wv = (const float*)d_in[9];
    const float* bv = (const float*)d_in[10];
    const float* scale_q = (const float*)d_in[11];
    const float* scale_k = (const float*)d_in[12];
    const float* wo = (const float*)d_in[13];
    const float* bo = (const float*)d_in[14];
    float* out = (float*)d_out;

    char* ws = (char*)d_ws;
    size_t off = 0;
    auto alloc = [&](size_t bytes) {
        void* p = ws + off;
        off += (bytes + 255) & ~(size_t)255;
        return p;
    };
    const size_t MD = (size_t)B_ * T_ * D_;
    __bf16* qb16  = (__bf16*)alloc(MD * 2);
    __bf16* kvb16 = (__bf16*)alloc(MD * 2);
    __bf16* wqT = (__bf16*)alloc((size_t)D_ * D_ * 2);
    __bf16* wkT = (__bf16*)alloc((size_t)D_ * D_ * 2);
    __bf16* wvT = (__bf16*)alloc((size_t)D_ * D_ * 2);
    __bf16* woT = (__bf16*)alloc((size_t)D_ * D_ * 2);
    __bf16* qh  = (__bf16*)alloc(MD * 2);
    __bf16* kh  = (__bf16*)alloc(MD * 2);
    __bf16* vt  = (__bf16*)alloc(MD * 2);
    float2* rtab = (float2*)alloc((size_t)T_ * 32 * sizeof(float2));
    __bf16* attn = qb16;  // reuse: qb16 dead after the Q GEMM

    cast_kernel<<<2048, 256, 0, stream>>>(q, qb16, (int)(MD / 4));
    cast_kernel<<<2048, 256, 0, stream>>>(kv, kvb16, (int)(MD / 4));
    dim3 twg(16, 16, 1);
    transpose_w_kernel<<<twg, 256, 0, stream>>>(wq, wqT, D_, D_);
    transpose_w_kernel<<<twg, 256, 0, stream>>>(wk, wkT, D_, D_);
    transpose_w_kernel<<<twg, 256, 0, stream>>>(wv, wvT, D_, D_);
    transpose_w_kernel<<<twg, 256, 0, stream>>>(wo, woT, D_, D_);
    rope_table_kernel<<<(T_ * 32) / 256, 256, 0, stream>>>(rtab);

    const int M = B_ * T_;
    const int gemm_blocks = (M / 128) * (D_ / 128);  // 256

    // Q path: GEMM + fused RMSNorm/RoPE -> qh
    gemm_tile_kernel<1><<<gemm_blocks, 256, 0, stream>>>(
        qb16, wqT, bq, nullptr, qh, scale_q, qpos, rtab, M, D_, D_);
    // K path -> kh
    gemm_tile_kernel<1><<<gemm_blocks, 256, 0, stream>>>(
        kvb16, wkT, bk, nullptr, kh, scale_k, kpos, rtab, M, D_, D_);
    // V path -> vt (transposed bf16)
    gemm_tile_kernel<2><<<gemm_blocks, 256, 0, stream>>>(
        kvb16, wvT, bv, nullptr, vt, nullptr, nullptr, nullptr, M, D_, D_);
    // attention
    attn_kernel<<<dim3(16, B_ * H_), 256, 0, stream>>>(qh, kh, vt, attn);
    // output projection -> fp32 out
    gemm_tile_kernel<0><<<gemm_blocks, 256, 0, stream>>>(
        attn, woT, bo, out, nullptr, nullptr, nullptr, nullptr, M, D_, D_);
}

// Round 4
// 96.527 us; speedup vs baseline: 4.7609x; 1.5529x over previous
//
#include <hip/hip_runtime.h>
#include <hip/hip_bf16.h>
#include <cstdint>

#define B_ 4
#define T_ 2048
#define D_ 512
#define H_ 8

typedef __bf16 bf16x8 __attribute__((ext_vector_type(8)));
typedef __bf16 bf16x4 __attribute__((ext_vector_type(4)));
typedef float f32x4 __attribute__((ext_vector_type(4)));

__device__ inline void gload_lds16(const void* g, void* l) {
    __builtin_amdgcn_global_load_lds(
        (const __attribute__((address_space(1))) void*)g,
        (__attribute__((address_space(3))) void*)l, 16, 0, 0);
}

// ---------------- cast fp32 -> bf16 for q and kv in one launch ----------------
__global__ void cast2_kernel(const float* __restrict__ qf, const float* __restrict__ kvf,
                             __bf16* __restrict__ qb, __bf16* __restrict__ kvb, int n4) {
    int stride = gridDim.x * blockDim.x;
    for (int i = blockIdx.x * blockDim.x + threadIdx.x; i < 2 * n4; i += stride) {
        const float* src = (i < n4) ? qf : kvf;
        __bf16* dst = (i < n4) ? qb : kvb;
        int j = (i < n4) ? i : i - n4;
        float4 v = reinterpret_cast<const float4*>(src)[j];
        bf16x4 o = { (__bf16)v.x, (__bf16)v.y, (__bf16)v.z, (__bf16)v.w };
        reinterpret_cast<bf16x4*>(dst)[j] = o;
    }
}

// ---------------- transpose all 4 weights (z selects) ----------------
__global__ void transpose_w4_kernel(const float* __restrict__ wq, const float* __restrict__ wk,
                                    const float* __restrict__ wv, const float* __restrict__ wo,
                                    __bf16* __restrict__ wqkvT, __bf16* __restrict__ woT) {
    __shared__ float tile[32][33];
    int z = blockIdx.z;
    const float* in = (z == 0) ? wq : (z == 1) ? wk : (z == 2) ? wv : wo;
    __bf16* out = (z < 3) ? wqkvT + (size_t)z * D_ * D_ : woT;
    int tx = threadIdx.x & 31, ty = threadIdx.x >> 5;
    int r0 = blockIdx.y * 32, c0 = blockIdx.x * 32;
#pragma unroll
    for (int i = 0; i < 4; i++)
        tile[ty + i * 8][tx] = in[(size_t)(r0 + ty + i * 8) * D_ + c0 + tx];
    __syncthreads();
#pragma unroll
    for (int i = 0; i < 4; i++)
        out[(size_t)(c0 + ty + i * 8) * D_ + r0 + tx] = (__bf16)tile[tx][ty + i * 8];
}

// ---------------- RoPE cos/sin table ----------------
__global__ void rope_table_kernel(float2* __restrict__ tab) {
    int i = blockIdx.x * 256 + threadIdx.x;     // T*32 entries
    int p = i >> 5, d2 = i & 31;
    float inv_ts = exp2f((float)d2 * (-13.28771237954945f / 32.0f));
    float ang = (float)p * inv_ts;
    float sv, cv;
    __sincosf(ang, &sv, &cv);
    tab[i] = make_float2(cv, sv);
}

// ---------------- tiled GEMM: 128x128 tile, BK=32, double-buffered LDS ----------------
// MODE 0: out = X @ woT^T + bo -> fp32 [M][512]
// MODE 3: fused QKV: WT is [1536][512]; segment 0/1 -> RMSNorm+RoPE bf16 heads,
//         segment 2 -> V transposed bf16 [B*H][64][T]
template<int MODE>
__global__ __launch_bounds__(256, 2) void gemm_tile_kernel(
    const __bf16* __restrict__ Xq, const __bf16* __restrict__ Xkv,
    const __bf16* __restrict__ WT,
    const float* __restrict__ biasQ, const float* __restrict__ biasK,
    const float* __restrict__ biasV,
    float* __restrict__ outf, __bf16* __restrict__ qh, __bf16* __restrict__ kh,
    __bf16* __restrict__ vt,
    const float* __restrict__ scale_q, const float* __restrict__ scale_k,
    const int* __restrict__ qpos, const int* __restrict__ kpos,
    const float2* __restrict__ rtab, int M, int Ntot, int K) {
    __shared__ __bf16 Ab[2][128 * 32];
    __shared__ __bf16 Bb[2][128 * 32];

    const int tid = threadIdx.x;
    const int lane = tid & 63, widx = tid >> 6;
    const int lo = lane & 15, hi = lane >> 4;
    const int wm = widx >> 1, wn = widx & 1;

    // bijective XCD swizzle (gridDim.x % 8 == 0)
    const int nwg = gridDim.x;
    const int q8 = nwg >> 3;
    int bid = blockIdx.x;
    int swz = (bid & 7) * q8 + (bid >> 3);
    const int ntn = Ntot >> 7;
    const int m0 = (swz / ntn) << 7;
    const int nt = swz % ntn;
    const int n0g = nt << 7;                       // row base in WT
    const int seg = (MODE == 3) ? (nt >> 2) : 0;   // 0:Q 1:K 2:V
    const __bf16* X = (MODE == 3 && seg > 0) ? Xkv : Xq;

    const int srow = tid >> 2;
    const int sslot = tid & 3;

    f32x4 acc[4][4] = {};

    auto stage = [&](int kc, int bufi) {
#pragma unroll
        for (int i = 0; i < 2; i++) {
            int row = i * 64 + srow;
            int cs = sslot ^ ((row >> 1) & 3);
            gload_lds16(X + (size_t)(m0 + row) * K + kc + cs * 8,
                        &Ab[bufi][(i * 64 + widx * 16) * 32]);
        }
#pragma unroll
        for (int i = 0; i < 2; i++) {
            int row = i * 64 + srow;
            int cs = sslot ^ ((row >> 1) & 3);
            gload_lds16(WT + (size_t)(n0g + row) * K + kc + cs * 8,
                        &Bb[bufi][(i * 64 + widx * 16) * 32]);
        }
    };

    const int nks = K >> 5;
    stage(0, 0);
    __syncthreads();
    int cur = 0;

    for (int ks = 0; ks < nks; ks++) {
        if (ks + 1 < nks) stage((ks + 1) << 5, cur ^ 1);

        bf16x8 a[4], bvec[4];
#pragma unroll
        for (int mf = 0; mf < 4; mf++) {
            int R = wm * 64 + mf * 16 + lo;
            a[mf] = *reinterpret_cast<const bf16x8*>(&Ab[cur][R * 32 + ((hi ^ ((R >> 1) & 3)) << 3)]);
        }
#pragma unroll
        for (int nf = 0; nf < 4; nf++) {
            int R = wn * 64 + nf * 16 + lo;
            bvec[nf] = *reinterpret_cast<const bf16x8*>(&Bb[cur][R * 32 + ((hi ^ ((R >> 1) & 3)) << 3)]);
        }
#pragma unroll
        for (int mf = 0; mf < 4; mf++)
#pragma unroll
            for (int nf = 0; nf < 4; nf++)
                acc[mf][nf] = __builtin_amdgcn_mfma_f32_16x16x32_bf16(a[mf], bvec[nf], acc[mf][nf], 0, 0, 0);

        __syncthreads();
        cur ^= 1;
    }

    const int mrow0 = m0 + wm * 64;

    if (MODE == 0) {
        const int ncol0 = n0g + wn * 64;
        float bs[4];
#pragma unroll
        for (int nf = 0; nf < 4; nf++) bs[nf] = biasQ[ncol0 + nf * 16 + lo];
#pragma unroll
        for (int mf = 0; mf < 4; mf++)
#pragma unroll
            for (int nf = 0; nf < 4; nf++)
#pragma unroll
                for (int r = 0; r < 4; r++) {
                    int row = mrow0 + mf * 16 + hi * 4 + r;
                    outf[(size_t)row * Ntot + ncol0 + nf * 16 + lo] = acc[mf][nf][r] + bs[nf];
                }
    } else {
        const int ncol0 = ((nt & 3) << 7) + wn * 64;   // within 512-wide segment
        const int h = ncol0 >> 6;
        const float* bias = (seg == 0) ? biasQ : (seg == 1) ? biasK : biasV;
        float bs[4];
#pragma unroll
        for (int nf = 0; nf < 4; nf++) bs[nf] = bias[ncol0 + nf * 16 + lo];

        if (seg < 2) {
            const float* scale = seg ? scale_k : scale_q;
            const int* pos = seg ? kpos : qpos;
            __bf16* dst0 = seg ? kh : qh;
            float sc4[4];
#pragma unroll
            for (int nf = 0; nf < 4; nf++) sc4[nf] = 1.0f + scale[nf * 16 + lo];
#pragma unroll
            for (int mf = 0; mf < 4; mf++) {
#pragma unroll
                for (int r = 0; r < 4; r++) {
                    int row = mrow0 + mf * 16 + hi * 4 + r;
                    float y0 = acc[mf][0][r] + bs[0];
                    float y1 = acc[mf][1][r] + bs[1];
                    float y2 = acc[mf][2][r] + bs[2];
                    float y3 = acc[mf][3][r] + bs[3];
                    float ps = y0 * y0 + y1 * y1 + y2 * y2 + y3 * y3;
#pragma unroll
                    for (int off = 1; off < 16; off <<= 1) ps += __shfl_xor(ps, off);
                    float rmsf = rsqrtf(ps * (1.0f / 64.0f) + 1e-6f);
                    int p = pos[row];
                    float2 c0 = rtab[p * 32 + lo];
                    float2 c1 = rtab[p * 32 + 16 + lo];
                    float z0 = y0 * rmsf * sc4[0];
                    float z1 = y1 * rmsf * sc4[1];
                    float z2 = y2 * rmsf * sc4[2];
                    float z3 = y3 * rmsf * sc4[3];
                    int b = row >> 11, t = row & (T_ - 1);
                    __bf16* dst = dst0 + ((size_t)(b * H_ + h) * T_ + t) * 64;
                    dst[lo]      = (__bf16)(z0 * c0.x - z2 * c0.y);
                    dst[16 + lo] = (__bf16)(z1 * c1.x - z3 * c1.y);
                    dst[32 + lo] = (__bf16)(z2 * c0.x + z0 * c0.y);
                    dst[48 + lo] = (__bf16)(z3 * c1.x + z1 * c1.y);
                }
            }
        } else {
#pragma unroll
            for (int mf = 0; mf < 4; mf++) {
                int row0 = mrow0 + mf * 16 + hi * 4;
                int b = row0 >> 11, t0 = row0 & (T_ - 1);
#pragma unroll
                for (int nf = 0; nf < 4; nf++) {
                    int d = nf * 16 + lo;
                    bf16x4 pk = { (__bf16)(acc[mf][nf][0] + bs[nf]), (__bf16)(acc[mf][nf][1] + bs[nf]),
                                  (__bf16)(acc[mf][nf][2] + bs[nf]), (__bf16)(acc[mf][nf][3] + bs[nf]) };
                    *reinterpret_cast<bf16x4*>(vt + ((size_t)(b * H_ + h) * 64 + d) * T_ + t0) = pk;
                }
            }
        }
    }
}

// ---------------- causal flash attention: swapped QK^T, lane-local softmax ----------------
// qh, kh: bf16 [B*H][T][64]; vt: bf16 [B*H][64][T]; attn out bf16 [B*T][512].
// One block = one 64-row strip (4 waves x 16 q). Longest strips first.
// S^T = mfma(K,Q): lane (lo,hi) holds S[q=lo][kv=f*16+hi*4+r] -> in-lane softmax
// (15 fmax + 2 shfl), scalar m,l per lane. O^T = mfma(V^T, P).
__global__ __launch_bounds__(256, 3) void attn_kernel(const __bf16* __restrict__ qh,
                                                      const __bf16* __restrict__ kh,
                                                      const __bf16* __restrict__ vt,
                                                      __bf16* __restrict__ attn) {
    __shared__ __bf16 kbuf[2][64 * 64];
    __shared__ __bf16 vbuf[2][64 * 64];
    __shared__ __bf16 plds[4][16][72];   // 144B rows: 16B-aligned, 2-way-free banks

    const int lane = threadIdx.x & 63, widx = threadIdx.x >> 6;
    const int lo = lane & 15, hi = lane >> 4;
    const int bh = blockIdx.x;
    const int sid = 31 - blockIdx.y;          // longest strips dispatched first
    const int ntiles = sid + 1;
    const int qb = sid * 64 + widx * 16;
    const __bf16* Qg = qh + (size_t)bh * T_ * 64;
    const __bf16* Kg = kh + (size_t)bh * T_ * 64;
    const __bf16* Vg = vt + (size_t)bh * 64 * T_;
    const int b = bh >> 3, h = bh & 7;

    const int srow = lane >> 3;
    const int sslot = lane & 7;
    const int schunk = sslot ^ srow;

    bf16x8 qa[2];
#pragma unroll
    for (int c = 0; c < 2; c++)
        qa[c] = *reinterpret_cast<const bf16x8*>(Qg + (size_t)(qb + lo) * 64 + c * 32 + hi * 8);

    f32x4 o[4] = {};
    float m = -1e30f, l = 0.0f;

    auto stage = [&](int tile, int bufi) {
        const int kvb0 = tile * 64;
#pragma unroll
        for (int i = 0; i < 2; i++) {
            int r = widx * 16 + i * 8 + srow;
            gload_lds16(Kg + (size_t)(kvb0 + r) * 64 + schunk * 8,
                        &kbuf[bufi][(widx * 16 + i * 8) * 64]);
        }
#pragma unroll
        for (int i = 0; i < 2; i++) {
            int r = widx * 16 + i * 8 + srow;
            gload_lds16(Vg + (size_t)r * T_ + kvb0 + schunk * 8,
                        &vbuf[bufi][(widx * 16 + i * 8) * 64]);
        }
    };

    stage(0, 0);
    __syncthreads();
    int cur = 0;

    for (int j = 0; j < ntiles; ++j) {
        if (j + 1 < ntiles) stage(j + 1, cur ^ 1);

        // ---- S^T = K x Q^T : s[f][r] = S[q=lo][kv=f*16+hi*4+r] ----
        f32x4 s[4] = {};
        __builtin_amdgcn_s_setprio(1);
#pragma unroll
        for (int c = 0; c < 2; c++) {
#pragma unroll
            for (int f = 0; f < 4; f++) {
                int R = f * 16 + lo;
                int C = c * 4 + hi;
                bf16x8 kb = *reinterpret_cast<const bf16x8*>(
                    &kbuf[cur][R * 64 + ((C ^ (lo & 7)) << 3)]);
                s[f] = __builtin_amdgcn_mfma_f32_16x16x32_bf16(kb, qa[c], s[f], 0, 0, 0);
            }
        }
        __builtin_amdgcn_s_setprio(0);

        // ---- mask (diag tile only) + in-lane max ----
        const bool diag = (j == ntiles - 1);
        float pm = -1e30f;
#pragma unroll
        for (int f = 0; f < 4; f++)
#pragma unroll
            for (int r = 0; r < 4; r++) {
                float v = s[f][r];
                if (diag && (f * 16 + hi * 4 + r > widx * 16 + lo)) v = -1e30f;
                s[f][r] = v;
                pm = fmaxf(pm, v);
            }
        pm = fmaxf(pm, __shfl_xor(pm, 16));
        pm = fmaxf(pm, __shfl_xor(pm, 32));

        // ---- defer-max (T13): raw threshold 64 = 8 / 0.125 ----
        if (!__all(pm <= m + 64.0f)) {
            float mn = fmaxf(m, pm);
            float alpha = __expf((m - mn) * 0.125f);
            l *= alpha;
#pragma unroll
            for (int n = 0; n < 4; n++)
#pragma unroll
                for (int r = 0; r < 4; r++) o[n][r] *= alpha;
            m = mn;
        }

        // ---- exp + in-lane sum + P pack ----
        const float negm = -m * 0.125f;
        float ps = 0.0f;
        bf16x4 pk[4];
#pragma unroll
        for (int f = 0; f < 4; f++) {
#pragma unroll
            for (int r = 0; r < 4; r++) {
                float e = __expf(fmaf(s[f][r], 0.125f, negm));
                ps += e;
                pk[f][r] = (__bf16)e;
            }
        }
        ps += __shfl_xor(ps, 16);
        ps += __shfl_xor(ps, 32);
        l += ps;

        // ---- P -> LDS (packed b64 writes) -> B-fragments ----
#pragma unroll
        for (int f = 0; f < 4; f++)
            *reinterpret_cast<bf16x4*>(&plds[widx][lo][f * 16 + hi * 4]) = pk[f];
        bf16x8 pa0 = *reinterpret_cast<const bf16x8*>(&plds[widx][lo][hi * 8]);
        bf16x8 pa1 = *reinterpret_cast<const bf16x8*>(&plds[widx][lo][32 + hi * 8]);

        // ---- O^T += V^T x P^T ----
        __builtin_amdgcn_s_setprio(1);
#pragma unroll
        for (int n = 0; n < 4; n++) {
#pragma unroll
            for (int c = 0; c < 2; c++) {
                int R = n * 16 + lo;
                int C = c * 4 + hi;
                bf16x8 vb = *reinterpret_cast<const bf16x8*>(
                    &vbuf[cur][R * 64 + ((C ^ (lo & 7)) << 3)]);
                o[n] = __builtin_amdgcn_mfma_f32_16x16x32_bf16(vb, c ? pa1 : pa0, o[n], 0, 0, 0);
            }
        }
        __builtin_amdgcn_s_setprio(0);

        __syncthreads();
        cur ^= 1;
    }

    const float inv = 1.0f / l;
    const int qrow = qb + lo;
#pragma unroll
    for (int n = 0; n < 4; n++) {
        bf16x4 pk = { (__bf16)(o[n][0] * inv), (__bf16)(o[n][1] * inv),
                      (__bf16)(o[n][2] * inv), (__bf16)(o[n][3] * inv) };
        *reinterpret_cast<bf16x4*>(attn + ((size_t)b * T_ + qrow) * D_ + h * 64 + n * 16 + hi * 4) = pk;
    }
}

extern "C" void kernel_launch(void* const* d_in, const int* in_sizes, int n_in,
                              void* d_out, int out_size, void* d_ws, size_t ws_size,
                              hipStream_t stream) {
    const float* q  = (const float*)d_in[0];
    const float* kv = (const float*)d_in[1];
    const int* qpos = (const int*)d_in[3];
    const int* kpos = (const int*)d_in[4];
    const float* wq = (const float*)d_in[5];
    const float* bq = (const float*)d_in[6];
    const float* wk = (const float*)d_in[7];
    const float* bk = (const float*)d_in[8];
    const float* wv = (const float*)d_in[9];
    const float* bv = (const float*)d_in[10];
    const float* scale_q = (const float*)d_in[11];
    const float* scale_k = (const float*)d_in[12];
    const float* wo = (const float*)d_in[13];
    const float* bo = (const float*)d_in[14];
    float* out = (float*)d_out;

    char* ws = (char*)d_ws;
    size_t off = 0;
    auto alloc = [&](size_t bytes) {
        void* p = ws + off;
        off += (bytes + 255) & ~(size_t)255;
        return p;
    };
    const size_t MD = (size_t)B_ * T_ * D_;
    __bf16* qb16   = (__bf16*)alloc(MD * 2);
    __bf16* kvb16  = (__bf16*)alloc(MD * 2);
    __bf16* wqkvT  = (__bf16*)alloc((size_t)3 * D_ * D_ * 2);
    __bf16* woT    = (__bf16*)alloc((size_t)D_ * D_ * 2);
    __bf16* qh  = (__bf16*)alloc(MD * 2);
    __bf16* kh  = (__bf16*)alloc(MD * 2);
    __bf16* vt  = (__bf16*)alloc(MD * 2);
    float2* rtab = (float2*)alloc((size_t)T_ * 32 * sizeof(float2));
    __bf16* attn = qb16;  // reuse: qb16 dead after QKV GEMM

    cast2_kernel<<<2048, 256, 0, stream>>>(q, kv, qb16, kvb16, (int)(MD / 4));
    transpose_w4_kernel<<<dim3(16, 16, 4), 256, 0, stream>>>(wq, wk, wv, wo, wqkvT, woT);
    rope_table_kernel<<<(T_ * 32) / 256, 256, 0, stream>>>(rtab);

    const int M = B_ * T_;
    // fused QKV projection + RMSNorm/RoPE/V-transpose epilogues: N=1536 -> 768 blocks
    gemm_tile_kernel<3><<<(M / 128) * (3 * D_ / 128), 256, 0, stream>>>(
        qb16, kvb16, wqkvT, bq, bk, bv, nullptr, qh, kh, vt,
        scale_q, scale_k, qpos, kpos, rtab, M, 3 * D_, D_);
    // attention: grid (bh, strip), longest strips first
    attn_kernel<<<dim3(B_ * H_, 32), 256, 0, stream>>>(qh, kh, vt, attn);
    // output projection
    gemm_tile_kernel<0><<<(M / 128) * (D_ / 128), 256, 0, stream>>>(
        attn, nullptr, woT, bo, nullptr, nullptr, out, nullptr, nullptr, nullptr,
        nullptr, nullptr, nullptr, nullptr, nullptr, M, D_, D_);
}